// Round 3
// baseline (39.532 us; speedup 1.0000x reference)
//
#include <hip/hip_runtime.h>
#include <math.h>

// Geometry fixed by reference setup_inputs
#define GG 52
#define AA 3
#define BB 16
#define DD 85                      // 5 + 80 classes
#define NCELL (GG*GG*AA)           // 8112 cells per batch
#define EBAT (NCELL*DD)            // 689520 floats per batch
#define VEC_PB (EBAT/4)            // 172380 float4s per batch
#define BPB 128                    // blocks per batch
#define NBLK (BPB*BB)              // 2048 blocks total
#define NT 256
#define STRIDE (BPB*NT)            // 32768 threads per batch

// ln(1 + exp(-|x|)) : one HW exp + degree-5 poly (A&S 4.1.43, |err|<=1e-5 on [0,1])
__device__ __forceinline__ float softplus_nabs(float x) {
  float u = __expf(-fabsf(x));
  float p = fmaf(u, 0.03215845f, -0.13606275f);
  p = fmaf(u, p, 0.28947478f);
  p = fmaf(u, p, -0.49190896f);
  p = fmaf(u, p, 0.99949556f);
  return u * p;
}
__device__ __forceinline__ float fast_sig(float x) {
  float u = __expf(-fabsf(x));
  float r = __builtin_amdgcn_rcpf(1.0f + u);
  return x >= 0.0f ? r : u * r;
}

struct Acc { float s1, s2, cb, ob; };

// Process one float4 pair (y_pred, y_true) covering elements [i0, i0+3] of batch b.
__device__ __forceinline__ void proc4(unsigned i0, float4 p4, float4 t4,
                                      const float* __restrict__ ytb,
                                      float lw0, float lw1, float lw2,
                                      float lh0, float lh1, float lh2,
                                      Acc& a) {
  #pragma unroll
  for (int k = 0; k < 4; ++k) {
    unsigned i = i0 + k;
    unsigned cell = i / 85u;              // compiler magic-mul
    unsigned c = i - cell * 85u;
    float x = (&p4.x)[k];
    float t = (&t4.x)[k];
    // BCE(sigmoid(x), t) = max(x,0) - x*t + ln(1+exp(-|x|))
    float bce = fmaxf(x, 0.0f) - x * t + softplus_nabs(x);
    a.cb += (c >= 5u) ? bce : 0.0f;
    a.ob += (c == 4u) ? bce : 0.0f;
    a.s2 += (c == 4u) ? t : 0.0f;
    if (c < 4u) {                         // box regression channels, ~3/64 lanes
      float obj = ytb[cell * 85u + 4u];
      float s = fast_sig(x);
      float tgt;
      if (c < 2u) {
        unsigned gi = cell / 156u;        // cell / (G*A)  : meshgrid 'ij' dim-1
        unsigned gj = (cell / 3u) % 52u;  // dim-2
        tgt = t * 52.0f - (float)(c == 0u ? gi : gj);
      } else {
        unsigned ai = cell % 3u;
        float la = (c == 2u) ? (ai == 0u ? lw0 : (ai == 1u ? lw1 : lw2))
                             : (ai == 0u ? lh0 : (ai == 1u ? lh1 : lh2));
        tgt = (t > 0.0f) ? (__logf(t) - la) : 0.0f;
      }
      float d = tgt - s;
      a.s1 = fmaf(d * d, obj, a.s1);
    }
  }
}

__global__ __launch_bounds__(NT) void yolo_main(
    const float* __restrict__ yp, const float* __restrict__ yt,
    const float* __restrict__ anch, float* __restrict__ part)
{
  const int b = blockIdx.y;
  const float* __restrict__ ypb = yp + (size_t)b * EBAT;
  const float* __restrict__ ytb = yt + (size_t)b * EBAT;
  const float4* __restrict__ vp = (const float4*)ypb;
  const float4* __restrict__ vt = (const float4*)ytb;

  const float lw0 = __logf(anch[0]), lh0 = __logf(anch[1]);
  const float lw1 = __logf(anch[2]), lh1 = __logf(anch[3]);
  const float lw2 = __logf(anch[4]), lh2 = __logf(anch[5]);

  Acc a = {0.f, 0.f, 0.f, 0.f};

  int v = blockIdx.x * NT + threadIdx.x;
  // paired grid-stride: 4 x 16B loads in flight per iteration
  while (v + STRIDE < VEC_PB) {
    float4 pa = vp[v], ta = vt[v];
    float4 pb = vp[v + STRIDE], tb = vt[v + STRIDE];
    proc4(4u * v, pa, ta, ytb, lw0, lw1, lw2, lh0, lh1, lh2, a);
    proc4(4u * (v + STRIDE), pb, tb, ytb, lw0, lw1, lw2, lh0, lh1, lh2, a);
    v += 2 * STRIDE;
  }
  if (v < VEC_PB) {
    float4 pa = vp[v], ta = vt[v];
    proc4(4u * v, pa, ta, ytb, lw0, lw1, lw2, lh0, lh1, lh2, a);
  }

  // block reduce 4 values
  float v0 = a.s1, v1 = a.s2, v2 = a.cb, v3 = a.ob;
  for (int off = 32; off > 0; off >>= 1) {
    v0 += __shfl_down(v0, off); v1 += __shfl_down(v1, off);
    v2 += __shfl_down(v2, off); v3 += __shfl_down(v3, off);
  }
  __shared__ float lds[NT / 64][4];
  int lane = threadIdx.x & 63, wid = threadIdx.x >> 6;
  if (lane == 0) { lds[wid][0] = v0; lds[wid][1] = v1; lds[wid][2] = v2; lds[wid][3] = v3; }
  __syncthreads();
  if (threadIdx.x == 0) {
    float r0 = 0, r1 = 0, r2 = 0, r3 = 0;
    #pragma unroll
    for (int w = 0; w < NT / 64; ++w) {
      r0 += lds[w][0]; r1 += lds[w][1]; r2 += lds[w][2]; r3 += lds[w][3];
    }
    int pid = b * BPB + blockIdx.x;
    part[pid * 4 + 0] = r0;
    part[pid * 4 + 1] = r1;
    part[pid * 4 + 2] = r2;
    part[pid * 4 + 3] = r3;
  }
}

__global__ __launch_bounds__(256) void yolo_fin(
    const float* __restrict__ part, float* __restrict__ out)
{
  const int tid = threadIdx.x;
  float cb = 0.f, ob = 0.f;
  for (int i = tid; i < NBLK; i += 256) { cb += part[i * 4 + 2]; ob += part[i * 4 + 3]; }
  for (int off = 32; off > 0; off >>= 1) {
    cb += __shfl_down(cb, off); ob += __shfl_down(ob, off);
  }
  __shared__ float red[4][2];
  int lane = tid & 63, wid = tid >> 6;
  if (lane == 0) { red[wid][0] = cb; red[wid][1] = ob; }
  __syncthreads();
  __shared__ float coef;
  if (tid == 0) {
    float CB = red[0][0] + red[1][0] + red[2][0] + red[3][0];
    float OB = red[0][1] + red[1][1] + red[2][1] + red[3][1];
    const float ncls = (float)BB * (float)NCELL * 80.0f;   // 10,383,360 (<2^24, exact)
    const float nobj = (float)BB * (float)NCELL;           // 129,792
    coef = 0.5f * CB / ncls + OB / nobj;
  }
  __syncthreads();
  if (tid < BB) {
    float s1 = 0.f, s2 = 0.f;
    for (int j = 0; j < BPB; ++j) {
      int idx = (tid * BPB + j) * 4;
      s1 += part[idx + 0]; s2 += part[idx + 1];
    }
    out[tid] = 2.0f * s1 + coef * s2;
  }
}

extern "C" void kernel_launch(void* const* d_in, const int* in_sizes, int n_in,
                              void* d_out, int out_size, void* d_ws, size_t ws_size,
                              hipStream_t stream) {
  const float* yp   = (const float*)d_in[0];   // y_pred (16,52,52,3,85)
  const float* yt   = (const float*)d_in[1];   // y_true (16,52,52,3,85)
  const float* anch = (const float*)d_in[2];   // (3,2)
  float* out  = (float*)d_out;                 // (16,)
  float* part = (float*)d_ws;                  // NBLK*4 floats = 32 KB

  dim3 grid(BPB, BB);
  yolo_main<<<grid, NT, 0, stream>>>(yp, yt, anch, part);
  yolo_fin<<<1, 256, 0, stream>>>(part, out);
}